// Round 4
// baseline (260.602 us; speedup 1.0000x reference)
//
#include <hip/hip_runtime.h>
#include <hip/hip_cooperative_groups.h>
#include <math.h>

#define T_PTS 8192
#define NSOLVE 64
#define NLOG   16
#define NBLK   (NSOLVE + NLOG)
#define NTHR   512
#define NWAVE  (NTHR / 64)
#define NPT    256                // point-threads per block (2 halves share them)
#define PPT    4
#define WIN    (NPT * PPT)        // 1024-point window
#define CH     (T_PTS / NSOLVE)   // 128 owned points
#define HALO   ((WIN - CH) / 2)   // 448
#define BS     144                // 12 groups of 12 taps; 6 per half
#define NGH    6                  // tap-groups per half
#define ITERS  28                 // bound ~26, measured absmax 32 << 89
#define GL     144
#define LDSN   (GL + WIN + 144)   // 1312
#define BF     256                // logdet symbol band (validated R1-R3)
#define KCORR  768                // Szego modes (validated R1-R3)
#define KPERB  (KCORR / NLOG)     // 48

// ws: [0..23] acc{logdet0,szego,quad} f64 | 32 bar | 36 done | 64.. lg float[8192]

__device__ inline double blockReduceSum(double v, double* lds) {
#pragma unroll
    for (int o = 32; o > 0; o >>= 1) v += __shfl_down(v, o, 64);
    const int lane = threadIdx.x & 63, wid = threadIdx.x >> 6;
    __syncthreads();
    if (lane == 0) lds[wid] = v;
    __syncthreads();
    double r = 0.0;
    if (threadIdx.x == 0) {
#pragma unroll
        for (int i = 0; i < NWAVE; ++i) r += lds[i];
    }
    return r;   // valid on thread 0 only
}

struct SolverSh {
    float dbuf[2][LDSN];
    float pac[2][NPT][PPT];       // per-half partial ac
    float wv[BS];                 // wv[d-1] = w_d
    float lmax;
};
struct LogdetSh {
    float lgl[T_PTS];
    float wlg[BF + 1];
};
union ShMem { SolverSh s; LogdetSh l; };

__global__ __launch_bounds__(NTHR) void gp_mll_kernel(
    const float* __restrict__ y, const float* __restrict__ s2p,
    const float* __restrict__ ellp, const float* __restrict__ varp,
    float* __restrict__ out, unsigned char* __restrict__ wsb)
{
    __shared__ __align__(16) ShMem sh;
    __shared__ double redd[NWAVE];

    double* acc  = (double*)wsb;
    int*    bar  = (int*)(wsb + 32);
    int*    done = (int*)(wsb + 36);
    float*  lg   = (float*)(wsb + 64);

    const int tid = threadIdx.x, bid = blockIdx.x;
    const float sig2 = s2p[0], ell = ellp[0], var = varp[0];
    const float inv2l2 = 1.0f / (2.0f * ell * ell);

    if (bid < NSOLVE) {
        // ================= windowed Chebyshev solver, 2-way tap split =========
        SolverSh& S = sh.s;
        for (int d = tid; d < BS; d += NTHR)
            S.wv[d] = var * expf(-(float)((d + 1) * (d + 1)) * inv2l2);
        for (int i = tid; i < LDSN; i += NTHR) { S.dbuf[0][i] = 0.f; S.dbuf[1][i] = 0.f; }
        __syncthreads();
        if (tid == 0) {
            float s = 0.f;
            for (int d = 0; d < BS; ++d) s += S.wv[d];
            S.lmax = sig2 + var + 2.f * s;        // symbol sup >= lambda_max
        }
        __syncthreads();
        const float lmax = S.lmax, lmin = sig2;   // K PSD => lmin >= sigma^2
        const float theta = 0.5f * (lmax + lmin), delta = 0.5f * (lmax - lmin);
        const float s1 = theta / delta;
        const float invtheta = 1.f / theta;
        const float a0 = sig2 + var;

        const int pt   = tid & (NPT - 1);
        const int half = tid >> 8;                // 0 or 1 (wave-uniform)
        const int i0 = pt * PPT;
        const int g0 = bid * CH - HALO + i0;
        const int cb = GL + i0;                   // cb % 4 == 0

        float rr[PPT], xx[PPT], yv[PPT], mk[PPT];
#pragma unroll
        for (int p = 0; p < PPT; ++p) {
            const int g = g0 + p;
            const bool in = (g >= 0) && (g < T_PTS);
            yv[p] = in ? y[g] : 0.f;
            mk[p] = in ? 1.f : 0.f;
            rr[p] = yv[p]; xx[p] = 0.f;
            if (half == 0) S.dbuf[0][cb + p] = yv[p] * invtheta;
        }
        float rho = 1.f / s1;
        __syncthreads();

        const float4* wv4 = (const float4*)S.wv;
        float4* pac4 = (float4*)S.pac;
        for (int it = 0; it < ITERS; ++it) {
            const float* src = S.dbuf[it & 1];
            float*       dst = S.dbuf[(it + 1) & 1];
            const float4* s4 = (const float4*)src;

            float dk[PPT], ac[PPT];
            { float4 c = s4[cb >> 2]; dk[0]=c.x; dk[1]=c.y; dk[2]=c.z; dk[3]=c.w; }
#pragma unroll
            for (int p = 0; p < PPT; ++p) ac[p] = (half == 0) ? a0 * dk[p] : 0.f;

#pragma unroll
            for (int j = 0; j < NGH; ++j) {
                const int g = NGH * half + j;               // 0..11 across halves
                const int lb4 = (cb - 12 * g - 12) >> 2;    // 16B-aligned exact
                const int rb4 = (cb + 12 * g) >> 2;
                float la[16], ra[16], wg[12];
                float4 t;
                t = s4[lb4+0]; la[0]=t.x;  la[1]=t.y;  la[2]=t.z;  la[3]=t.w;
                t = s4[lb4+1]; la[4]=t.x;  la[5]=t.y;  la[6]=t.z;  la[7]=t.w;
                t = s4[lb4+2]; la[8]=t.x;  la[9]=t.y;  la[10]=t.z; la[11]=t.w;
                t = s4[lb4+3]; la[12]=t.x; la[13]=t.y; la[14]=t.z; la[15]=t.w;
                t = s4[rb4+0]; ra[0]=t.x;  ra[1]=t.y;  ra[2]=t.z;  ra[3]=t.w;
                t = s4[rb4+1]; ra[4]=t.x;  ra[5]=t.y;  ra[6]=t.z;  ra[7]=t.w;
                t = s4[rb4+2]; ra[8]=t.x;  ra[9]=t.y;  ra[10]=t.z; ra[11]=t.w;
                t = s4[rb4+3]; ra[12]=t.x; ra[13]=t.y; ra[14]=t.z; ra[15]=t.w;
                t = wv4[3*g+0]; wg[0]=t.x; wg[1]=t.y;  wg[2]=t.z;  wg[3]=t.w;
                t = wv4[3*g+1]; wg[4]=t.x; wg[5]=t.y;  wg[6]=t.z;  wg[7]=t.w;
                t = wv4[3*g+2]; wg[8]=t.x; wg[9]=t.y;  wg[10]=t.z; wg[11]=t.w;
                // tap d = 12g+1+k: src[cb+p-d] = la[11-k+p], src[cb+p+d] = ra[k+1+p]
#pragma unroll
                for (int k = 0; k < 12; ++k)
#pragma unroll
                    for (int p = 0; p < PPT; ++p)
                        ac[p] = fmaf(wg[k], la[11 - k + p] + ra[k + 1 + p], ac[p]);
            }
            pac4[half * NPT + pt] = make_float4(ac[0], ac[1], ac[2], ac[3]);
            __syncthreads();        // partials visible
            {
                float4 p0 = pac4[pt], p1 = pac4[NPT + pt];
                ac[0] = p0.x + p1.x; ac[1] = p0.y + p1.y;
                ac[2] = p0.z + p1.z; ac[3] = p0.w + p1.w;
            }
            const float rho1 = 1.f / (2.f * s1 - rho);
            const float c1 = rho1 * rho, c2 = 2.f * rho1 / delta;
            rho = rho1;
            float dn[PPT];
#pragma unroll
            for (int p = 0; p < PPT; ++p) {     // both halves keep identical state
                xx[p] += dk[p];
                rr[p] -= ac[p];
                dn[p] = mk[p] * (c1 * dk[p] + c2 * rr[p]);  // ghosts stay 0
            }
            if (half == 0)
                ((float4*)dst)[cb >> 2] = make_float4(dn[0], dn[1], dn[2], dn[3]);
            __syncthreads();        // dst visible; pac reusable next iter
        }

        // quad over OWNED points (half 0 only; half 1 contributes 0)
        double q = 0.0;
        if (half == 0) {
#pragma unroll
            for (int p = 0; p < PPT; ++p) {
                const int iw = i0 + p;
                if (iw >= HALO && iw < HALO + CH)
                    q += (double)yv[p] * (double)xx[p];
            }
        }
        const double qs = blockReduceSum(q, redd);
        if (tid == 0) atomicAdd(&acc[2], qs);
    } else {
        // ================= logdet: circulant + strong Szego =================
        LogdetSh& L = sh.l;
        const int lbk = bid - NSOLVE;
        for (int d = tid; d <= BF; d += NTHR)
            L.wlg[d] = var * expf(-(float)(d * d) * inv2l2);
        __syncthreads();
        const float ang0 = 7.66990393942820614859e-4f;   // 2*pi/8192
        const int j = lbk * NTHR + tid;                  // my frequency index
        float fj = sig2 + var;
        for (int d = 1; d <= BF; ++d) {
            int m = (j * d) & (T_PTS - 1);               // exact int phase
            if (m >= T_PTS / 2) m -= T_PTS;
            fj += 2.f * L.wlg[d] * cosf(ang0 * (float)m);
        }
        const float lgj = logf(fj);
        lg[j] = lgj;                                     // publish to ws
        const double ls = blockReduceSum((double)lgj, redd);
        if (tid == 0) atomicAdd(&acc[0], ls);            // circulant term
        __threadfence();                                 // release my lg store
        __syncthreads();
        if (tid == 0) {                                  // sub-barrier, NLOG blocks
            atomicAdd(bar, 1);
            while (__hip_atomic_load(bar, __ATOMIC_ACQUIRE, __HIP_MEMORY_SCOPE_AGENT) < NLOG)
                __builtin_amdgcn_s_sleep(8);
        }
        __syncthreads();
        for (int i = tid; i < T_PTS; i += NTHR) L.lgl[i] = lg[i];   // stage to LDS
        __syncthreads();
        double corr = 0.0;
        for (int t = 0; t < KPERB; ++t) {
            const int k = lbk * KPERB + t + 1;
            double p = 0.0;
            for (int jj = tid; jj < T_PTS; jj += NTHR) {
                int m = (jj * k) & (T_PTS - 1);
                if (m >= T_PTS / 2) m -= T_PTS;
                p += (double)(L.lgl[jj] * __cosf(ang0 * (float)m));
            }
            double ckv = blockReduceSum(p, redd);
            if (tid == 0) {
                ckv *= (1.0 / (double)T_PTS);
                corr += (double)k * ckv * ckv;
            }
        }
        if (tid == 0) atomicAdd(&acc[1], corr);
    }

    // ================= last-block combine =================
    __syncthreads();
    if (tid == 0) {
        __threadfence();
        const int old = atomicAdd(done, 1);
        if (old == NBLK - 1) {
            __threadfence();
            const double l0 = __hip_atomic_load(&acc[0], __ATOMIC_RELAXED, __HIP_MEMORY_SCOPE_AGENT);
            const double l1 = __hip_atomic_load(&acc[1], __ATOMIC_RELAXED, __HIP_MEMORY_SCOPE_AGENT);
            const double qq = __hip_atomic_load(&acc[2], __ATOMIC_RELAXED, __HIP_MEMORY_SCOPE_AGENT);
            out[0] = (float)(-0.5 * qq - 0.5 * (l0 + l1));
        }
    }
}

extern "C" void kernel_launch(void* const* d_in, const int* in_sizes, int n_in,
                              void* d_out, int out_size, void* d_ws, size_t ws_size,
                              hipStream_t stream) {
    const float* y    = (const float*)d_in[0];
    const float* sig2 = (const float*)d_in[1];
    const float* ell  = (const float*)d_in[2];
    const float* var  = (const float*)d_in[3];
    float* out = (float*)d_out;
    unsigned char* ws = (unsigned char*)d_ws;

    hipMemsetAsync(d_ws, 0, 64, stream);   // acc[3] + bar + done only

    void* args[] = { (void*)&y, (void*)&sig2, (void*)&ell, (void*)&var,
                     (void*)&out, (void*)&ws };
    hipLaunchCooperativeKernel((void*)gp_mll_kernel, dim3(NBLK), dim3(NTHR),
                               args, 0, stream);
}

// Round 5
// 211.570 us; speedup vs baseline: 1.2318x; 1.2318x over previous
//
#include <hip/hip_runtime.h>
#include <hip/hip_cooperative_groups.h>
#include <math.h>

#define T_PTS 8192
#define NSOLVE 64
#define NLOG   16
#define NBLK   (NSOLVE + NLOG)
#define NTHR   512
#define NWAVE  (NTHR / 64)
#define NPT    128                // point-threads (4 tap-quarters share them)
#define PPT    8
#define WIN    (NPT * PPT)        // 1024-point window
#define CH     (T_PTS / NSOLVE)   // 128 owned points
#define HALO   ((WIN - CH) / 2)   // 448
#define BS     144                // 12 groups of 12 taps; 3 per quarter
#define NGQ    3                  // tap-groups per quarter
#define ITERS  28                 // measured absmax 32 << 89 at 28
#define GL     144
#define LDSN   (GL + WIN + 152)   // 1320; max read idx 1311
#define BF     256                // logdet symbol band (validated R1-R4)
#define KCORR  768                // Szego modes (validated R1-R4)
#define KPERB  (KCORR / NLOG)     // 48

// ws: [0..23] acc{logdet0,szego,quad} f64 | 32 bar | 36 done | 64.. lg float[8192]

__device__ inline double blockReduceSum(double v, double* lds) {
#pragma unroll
    for (int o = 32; o > 0; o >>= 1) v += __shfl_down(v, o, 64);
    const int lane = threadIdx.x & 63, wid = threadIdx.x >> 6;
    __syncthreads();
    if (lane == 0) lds[wid] = v;
    __syncthreads();
    double r = 0.0;
    if (threadIdx.x == 0) {
#pragma unroll
        for (int i = 0; i < NWAVE; ++i) r += lds[i];
    }
    return r;   // valid on thread 0 only
}

struct SolverSh {
    float dbuf[2][LDSN];
    float pac[4][PPT][NPT];       // partial ac planes: [quarter][k][pt]
    float wv[BS];                 // wv[d-1] = w_d
    float lmax;
};
struct LogdetSh {
    float lgl[T_PTS];
    float wlg[BF + 1];
};
union ShMem { SolverSh s; LogdetSh l; };

__global__ __launch_bounds__(NTHR, 2) void gp_mll_kernel(
    const float* __restrict__ y, const float* __restrict__ s2p,
    const float* __restrict__ ellp, const float* __restrict__ varp,
    float* __restrict__ out, unsigned char* __restrict__ wsb)
{
    __shared__ __align__(16) ShMem sh;
    __shared__ double redd[NWAVE];

    double* acc  = (double*)wsb;
    int*    bar  = (int*)(wsb + 32);
    int*    done = (int*)(wsb + 36);
    float*  lg   = (float*)(wsb + 64);

    const int tid = threadIdx.x, bid = blockIdx.x;
    const float sig2 = s2p[0], ell = ellp[0], var = varp[0];
    const float inv2l2 = 1.0f / (2.0f * ell * ell);

    if (bid < NSOLVE) {
        // ============ windowed Chebyshev solver, 4-way tap split, b64 LDS ============
        SolverSh& S = sh.s;
        for (int d = tid; d < BS; d += NTHR)
            S.wv[d] = var * expf(-(float)((d + 1) * (d + 1)) * inv2l2);
        for (int i = tid; i < LDSN; i += NTHR) { S.dbuf[0][i] = 0.f; S.dbuf[1][i] = 0.f; }
        __syncthreads();
        if (tid == 0) {
            float s = 0.f;
            for (int d = 0; d < BS; ++d) s += S.wv[d];
            S.lmax = sig2 + var + 2.f * s;        // symbol sup >= lambda_max
        }
        __syncthreads();
        const float lmax = S.lmax, lmin = sig2;   // K PSD => lmin >= sigma^2
        const float theta = 0.5f * (lmax + lmin), delta = 0.5f * (lmax - lmin);
        const float s1 = theta / delta;
        const float invtheta = 1.f / theta;
        const float a0 = sig2 + var;

        const int pt = tid & (NPT - 1);
        const int q  = tid >> 7;                  // 0..3, wave-uniform (2 waves/quarter)
        const int i0 = pt * PPT;
        const int g0 = bid * CH - HALO + i0;
        const int cb = GL + i0;                   // cb % 8 == 0

        float rr[PPT], xx[PPT], yv[PPT], mk[PPT];
#pragma unroll
        for (int p = 0; p < PPT; ++p) {
            const int g = g0 + p;
            const bool in = (g >= 0) && (g < T_PTS);
            yv[p] = in ? y[g] : 0.f;
            mk[p] = in ? 1.f : 0.f;
            rr[p] = yv[p]; xx[p] = 0.f;
            if (q == 0) S.dbuf[0][cb + p] = yv[p] * invtheta;
        }
        float rho = 1.f / s1;
        __syncthreads();

        const float2* wv2 = (const float2*)S.wv;
        for (int it = 0; it < ITERS; ++it) {
            const float* src = S.dbuf[it & 1];
            float*       dst = S.dbuf[(it + 1) & 1];
            const float2* s2 = (const float2*)src;

            float dk[PPT], ac[PPT];
#pragma unroll
            for (int h = 0; h < 4; ++h) {
                float2 t = s2[(cb >> 1) + h];
                dk[2*h] = t.x; dk[2*h+1] = t.y;
            }
#pragma unroll
            for (int p = 0; p < PPT; ++p) ac[p] = (q == 0) ? a0 * dk[p] : 0.f;

#pragma unroll
            for (int j = 0; j < NGQ; ++j) {
                const int g = q * NGQ + j;                  // 0..11 across quarters
                const int Lb2 = (cb - 12 * g - 12) >> 1;    // float2 idx, exact (even)
                const int Rb2 = (cb + 12 * g) >> 1;
                float la[20], ra[20], wg[12];
#pragma unroll
                for (int h = 0; h < 10; ++h) {
                    float2 t = s2[Lb2 + h];
                    la[2*h] = t.x; la[2*h+1] = t.y;
                }
#pragma unroll
                for (int h = 0; h < 10; ++h) {
                    float2 t = s2[Rb2 + h];
                    ra[2*h] = t.x; ra[2*h+1] = t.y;
                }
#pragma unroll
                for (int h = 0; h < 6; ++h) {
                    float2 t = wv2[6 * g + h];              // broadcast
                    wg[2*h] = t.x; wg[2*h+1] = t.y;
                }
                // tap d = 12g+1+k: src[cb+p-d] = la[11-k+p], src[cb+p+d] = ra[k+1+p]
#pragma unroll
                for (int k = 0; k < 12; ++k)
#pragma unroll
                    for (int p = 0; p < PPT; ++p)
                        ac[p] = fmaf(wg[k], la[11 - k + p] + ra[k + 1 + p], ac[p]);
            }
            // publish partials as contiguous b32 planes (2-way banks: free)
#pragma unroll
            for (int k = 0; k < PPT; ++k) S.pac[q][k][pt] = ac[k];
            __syncthreads();
#pragma unroll
            for (int k = 0; k < PPT; ++k)
                ac[k] = S.pac[0][k][pt] + S.pac[1][k][pt]
                      + S.pac[2][k][pt] + S.pac[3][k][pt];

            const float rho1 = 1.f / (2.f * s1 - rho);
            const float c1 = rho1 * rho, c2 = 2.f * rho1 / delta;
            rho = rho1;
            float dn[PPT];
#pragma unroll
            for (int p = 0; p < PPT; ++p) {       // all quarters keep identical state
                xx[p] += dk[p];
                rr[p] -= ac[p];
                dn[p] = mk[p] * (c1 * dk[p] + c2 * rr[p]);  // ghosts stay 0
            }
            if (q == 0) {
                float2* d2 = (float2*)dst;
#pragma unroll
                for (int h = 0; h < 4; ++h)
                    d2[(cb >> 1) + h] = make_float2(dn[2*h], dn[2*h+1]);
            }
            __syncthreads();        // dst visible; pac reusable next iter
        }

        // quad over OWNED points (quarter 0 only)
        double qd = 0.0;
        if (q == 0) {
#pragma unroll
            for (int p = 0; p < PPT; ++p) {
                const int iw = i0 + p;
                if (iw >= HALO && iw < HALO + CH)
                    qd += (double)yv[p] * (double)xx[p];
            }
        }
        const double qs = blockReduceSum(qd, redd);
        if (tid == 0) atomicAdd(&acc[2], qs);
    } else {
        // ================= logdet: circulant + strong Szego =================
        LogdetSh& L = sh.l;
        const int lbk = bid - NSOLVE;
        for (int d = tid; d <= BF; d += NTHR)
            L.wlg[d] = var * expf(-(float)(d * d) * inv2l2);
        __syncthreads();
        const float ang0 = 7.66990393942820614859e-4f;   // 2*pi/8192
        const int j = lbk * NTHR + tid;                  // my frequency index
        float fj = sig2 + var;
        for (int d = 1; d <= BF; ++d) {
            int m = (j * d) & (T_PTS - 1);               // exact int phase
            if (m >= T_PTS / 2) m -= T_PTS;
            fj += 2.f * L.wlg[d] * cosf(ang0 * (float)m);
        }
        const float lgj = logf(fj);
        lg[j] = lgj;                                     // publish to ws
        const double ls = blockReduceSum((double)lgj, redd);
        if (tid == 0) atomicAdd(&acc[0], ls);            // circulant term
        __threadfence();                                 // release my lg store
        __syncthreads();
        if (tid == 0) {                                  // sub-barrier, NLOG blocks
            atomicAdd(bar, 1);
            while (__hip_atomic_load(bar, __ATOMIC_ACQUIRE, __HIP_MEMORY_SCOPE_AGENT) < NLOG)
                __builtin_amdgcn_s_sleep(8);
        }
        __syncthreads();
        for (int i = tid; i < T_PTS; i += NTHR) L.lgl[i] = lg[i];   // stage to LDS
        __syncthreads();
        double corr = 0.0;
        for (int t = 0; t < KPERB; ++t) {
            const int k = lbk * KPERB + t + 1;
            double p = 0.0;
            for (int jj = tid; jj < T_PTS; jj += NTHR) {
                int m = (jj * k) & (T_PTS - 1);
                if (m >= T_PTS / 2) m -= T_PTS;
                p += (double)(L.lgl[jj] * __cosf(ang0 * (float)m));
            }
            double ckv = blockReduceSum(p, redd);
            if (tid == 0) {
                ckv *= (1.0 / (double)T_PTS);
                corr += (double)k * ckv * ckv;
            }
        }
        if (tid == 0) atomicAdd(&acc[1], corr);
    }

    // ================= last-block combine =================
    __syncthreads();
    if (tid == 0) {
        __threadfence();
        const int old = atomicAdd(done, 1);
        if (old == NBLK - 1) {
            __threadfence();
            const double l0 = __hip_atomic_load(&acc[0], __ATOMIC_RELAXED, __HIP_MEMORY_SCOPE_AGENT);
            const double l1 = __hip_atomic_load(&acc[1], __ATOMIC_RELAXED, __HIP_MEMORY_SCOPE_AGENT);
            const double qq = __hip_atomic_load(&acc[2], __ATOMIC_RELAXED, __HIP_MEMORY_SCOPE_AGENT);
            out[0] = (float)(-0.5 * qq - 0.5 * (l0 + l1));
        }
    }
}

extern "C" void kernel_launch(void* const* d_in, const int* in_sizes, int n_in,
                              void* d_out, int out_size, void* d_ws, size_t ws_size,
                              hipStream_t stream) {
    const float* y    = (const float*)d_in[0];
    const float* sig2 = (const float*)d_in[1];
    const float* ell  = (const float*)d_in[2];
    const float* var  = (const float*)d_in[3];
    float* out = (float*)d_out;
    unsigned char* ws = (unsigned char*)d_ws;

    hipMemsetAsync(d_ws, 0, 64, stream);   // acc[3] + bar + done only

    void* args[] = { (void*)&y, (void*)&sig2, (void*)&ell, (void*)&var,
                     (void*)&out, (void*)&ws };
    hipLaunchCooperativeKernel((void*)gp_mll_kernel, dim3(NBLK), dim3(NTHR),
                               args, 0, stream);
}